// Round 4
// baseline (815.461 us; speedup 1.0000x reference)
//
#include <hip/hip_runtime.h>

#define DIM 512
#define NH 8
#define HD 64
#define LH 4
#define WIN 64
#define BATCH 4
#define SEQ 8192
#define NW (SEQ/WIN)   // 128

typedef unsigned short u16;
typedef __bf16 bf16x8 __attribute__((ext_vector_type(8)));
typedef float f32x4 __attribute__((ext_vector_type(4)));

__device__ __forceinline__ float b2f(u16 u) {
    return __uint_as_float(((unsigned int)u) << 16);
}
__device__ __forceinline__ u16 f2b(float f) {
    unsigned int x = __float_as_uint(f);
    return (u16)((x + 0x7FFFu + ((x >> 16) & 1u)) >> 16);
}

// fp32 -> bf16 conversion (inputs are fp32 per reference)
__global__ void convert_bf16(const float* __restrict__ src, u16* __restrict__ dst, long n)
{
    long i = ((long)blockIdx.x * 256 + threadIdx.x) * 8;
    const long stride = (long)gridDim.x * 256 * 8;
    for (; i < n; i += stride) {
        uint4 a = *(const uint4*)(src + i), b = *(const uint4*)(src + i + 4);
        const float* af = (const float*)&a;
        const float* bf_ = (const float*)&b;
        uint4 o; u16* ou = (u16*)&o;
        #pragma unroll
        for (int j = 0; j < 4; j++) { ou[j] = f2b(af[j]); ou[4 + j] = f2b(bf_[j]); }
        *(uint4*)(dst + i) = o;
    }
}

// ---------------------------------------------------------------------------
// Kernel A: q = x @ Wq^T, k = x @ Wkv^T (k == v). 64 rows x 128 cols / block.
// q,k written bf16 in (B,NH,SEQ,HD) head-split layout.
// ---------------------------------------------------------------------------
__global__ __launch_bounds__(256) void gemm_qk(const u16* __restrict__ xb,
        const u16* __restrict__ Wq, const u16* __restrict__ Wkv,
        u16* __restrict__ qh, u16* __restrict__ kh)
{
    const int wv = threadIdx.x >> 6, lane = threadIdx.x & 63;
    const int quad = lane >> 4, l16 = lane & 15;
    const int row0 = blockIdx.x * 64 + wv * 16;
    const int col0 = blockIdx.y * 128;

    f32x4 accq[8], acck[8];
    #pragma unroll
    for (int t = 0; t < 8; t++)
        for (int i = 0; i < 4; i++) { accq[t][i] = 0.f; acck[t][i] = 0.f; }

    const u16* xrow = xb + (size_t)(row0 + l16) * DIM + quad * 8;
    for (int kk = 0; kk < DIM; kk += 32) {
        bf16x8 a = *(const bf16x8*)(xrow + kk);
        #pragma unroll
        for (int t = 0; t < 8; t++) {
            bf16x8 bq = *(const bf16x8*)(Wq + (size_t)(col0 + t * 16 + l16) * DIM + kk + quad * 8);
            accq[t] = __builtin_amdgcn_mfma_f32_16x16x32_bf16(a, bq, accq[t], 0, 0, 0);
            bf16x8 bk = *(const bf16x8*)(Wkv + (size_t)(col0 + t * 16 + l16) * DIM + kk + quad * 8);
            acck[t] = __builtin_amdgcn_mfma_f32_16x16x32_bf16(a, bk, acck[t], 0, 0, 0);
        }
    }
    #pragma unroll
    for (int t = 0; t < 8; t++) {
        int col = col0 + t * 16 + l16;
        int h = col >> 6, e = col & 63;
        #pragma unroll
        for (int r = 0; r < 4; r++) {
            int row = row0 + quad * 4 + r;
            int b = row >> 13, n = row & (SEQ - 1);
            size_t idx = (((size_t)(b * NH + h)) * SEQ + n) * HD + e;
            qh[idx] = f2b(accq[t][r]);
            kh[idx] = f2b(acck[t][r]);
        }
    }
}

// ---------------------------------------------------------------------------
// Kernel B: local attention, one block per (b, h<4, window w). attn out fp32.
// ---------------------------------------------------------------------------
#define KJ_STRIDE 72
#define KT_STRIDE 200

__global__ __launch_bounds__(256) void local_attn(const u16* __restrict__ qh,
        const u16* __restrict__ kh, float* __restrict__ attn_out)
{
    __shared__ __align__(16) u16 kjP[192 * KJ_STRIDE];  // K-window [j][d], then P (stride 200)
    __shared__ __align__(16) u16 kT[64 * KT_STRIDE];    // V^T = K^T [e][j]

    const int w = blockIdx.x;
    const int bh = blockIdx.y;
    const int b = bh >> 2, h = bh & 3;
    const int tid = threadIdx.x;
    const int wv = tid >> 6, lane = tid & 63;
    const int quad = lane >> 4, l16 = lane & 15;

    for (int idx = tid; idx < 192 * 8; idx += 256) {
        int j = idx >> 3, dc = (idx & 7) << 3;
        int n = w * WIN - WIN + j;
        uint4 val = make_uint4(0, 0, 0, 0);
        if (n >= 0 && n < SEQ)
            val = *(const uint4*)(kh + (((size_t)(b * NH + h)) * SEQ + n) * HD + dc);
        *(uint4*)(&kjP[j * KJ_STRIDE + dc]) = val;
    }
    __syncthreads();
    for (int idx = tid; idx < 64 * 192; idx += 256) {
        int e = idx & 63, j = idx >> 6;
        kT[e * KT_STRIDE + j] = kjP[j * KJ_STRIDE + e];
    }
    __syncthreads();

    f32x4 s[12];
    #pragma unroll
    for (int t = 0; t < 12; t++)
        for (int i = 0; i < 4; i++) s[t][i] = 0.f;

    const u16* qrow = qh + (((size_t)(b * NH + h)) * SEQ + w * WIN + wv * 16 + l16) * HD + quad * 8;
    #pragma unroll
    for (int kk = 0; kk < 64; kk += 32) {
        bf16x8 a = *(const bf16x8*)(qrow + kk);
        #pragma unroll
        for (int t = 0; t < 12; t++) {
            bf16x8 bf = *(const bf16x8*)(&kjP[(t * 16 + l16) * KJ_STRIDE + kk + quad * 8]);
            s[t] = __builtin_amdgcn_mfma_f32_16x16x32_bf16(a, bf, s[t], 0, 0, 0);
        }
    }
    __syncthreads();

    const float scale = 0.125f;
    #pragma unroll
    for (int r = 0; r < 4; r++) {
        float vals[12];
        float mx = -3.0e38f;
        #pragma unroll
        for (int t = 0; t < 12; t++) {
            int j = t * 16 + l16;
            float v = s[t][r] * scale;
            bool valid = !((w == 0 && j < 64) || (w == NW - 1 && j >= 128));
            v = valid ? v : -30000.0f;
            vals[t] = v;
            mx = fmaxf(mx, v);
        }
        for (int m = 1; m <= 8; m <<= 1) mx = fmaxf(mx, __shfl_xor(mx, m));
        float sum = 0.f;
        #pragma unroll
        for (int t = 0; t < 12; t++) { vals[t] = __expf(vals[t] - mx); sum += vals[t]; }
        for (int m = 1; m <= 8; m <<= 1) sum += __shfl_xor(sum, m);
        float inv = 1.0f / sum;
        int prow = wv * 16 + quad * 4 + r;
        #pragma unroll
        for (int t = 0; t < 12; t++)
            kjP[prow * KT_STRIDE + t * 16 + l16] = f2b(vals[t] * inv);
    }
    __syncthreads();

    f32x4 o[4];
    #pragma unroll
    for (int t = 0; t < 4; t++)
        for (int i = 0; i < 4; i++) o[t][i] = 0.f;
    #pragma unroll
    for (int kc = 0; kc < 6; kc++) {
        bf16x8 a = *(const bf16x8*)(&kjP[(wv * 16 + l16) * KT_STRIDE + kc * 32 + quad * 8]);
        #pragma unroll
        for (int t = 0; t < 4; t++) {
            bf16x8 bf = *(const bf16x8*)(&kT[(t * 16 + l16) * KT_STRIDE + kc * 32 + quad * 8]);
            o[t] = __builtin_amdgcn_mfma_f32_16x16x32_bf16(a, bf, o[t], 0, 0, 0);
        }
    }
    #pragma unroll
    for (int t = 0; t < 4; t++) {
        int e = t * 16 + l16;
        #pragma unroll
        for (int r = 0; r < 4; r++) {
            int n = w * WIN + wv * 16 + quad * 4 + r;
            attn_out[(((size_t)(b * NH + h)) * SEQ + n) * HD + e] = o[t][r];
        }
    }
}

// ---------------------------------------------------------------------------
// Kernel C1: linear attention context accumulate.
// S[d][e] += sum_n exp(k[n,d]) * k[n,e]; colsum[d] += sum_n exp(k[n,d]).
// ---------------------------------------------------------------------------
__global__ __launch_bounds__(256) void ctx_accum(const u16* __restrict__ kh,
        float* __restrict__ S, float* __restrict__ colsum)
{
    const int chunk = blockIdx.x;
    const int bh = blockIdx.y;
    const int b = bh >> 2, hg = bh & 3;
    const int tid = threadIdx.x;
    const int d = tid >> 2, esub = tid & 3;
    const int r0 = tid >> 6, d2 = tid & 63;

    __shared__ float kraw[4][64];
    __shared__ float kexp[4][64];

    float acc[16];
    #pragma unroll
    for (int i = 0; i < 16; i++) acc[i] = 0.f;
    float csum = 0.f;

    const u16* kbase = kh + ((size_t)(b * NH + LH + hg)) * SEQ * HD;
    for (int n0 = chunk * 512; n0 < chunk * 512 + 512; n0 += 4) {
        __syncthreads();
        float v = b2f(kbase[(size_t)(n0 + r0) * HD + d2]);
        kraw[r0][d2] = v;
        kexp[r0][d2] = __expf(v);
        __syncthreads();
        #pragma unroll
        for (int r = 0; r < 4; r++) {
            float pd = kexp[r][d];
            if (esub == 0) csum += pd;
            #pragma unroll
            for (int j = 0; j < 4; j++) {
                f32x4 kv = *(const f32x4*)(&kraw[r][esub * 16 + j * 4]);
                acc[j * 4 + 0] += pd * kv[0];
                acc[j * 4 + 1] += pd * kv[1];
                acc[j * 4 + 2] += pd * kv[2];
                acc[j * 4 + 3] += pd * kv[3];
            }
        }
    }
    float* Sp = S + (size_t)bh * 4096 + d * 64 + esub * 16;
    #pragma unroll
    for (int i = 0; i < 16; i++) atomicAdd(Sp + i, acc[i]);
    if (esub == 0) atomicAdd(colsum + bh * 64 + d, csum);
}

// ---------------------------------------------------------------------------
// Kernel C2: linear attention output, fp32 attn out.
// ---------------------------------------------------------------------------
__global__ __launch_bounds__(256) void global_out(const u16* __restrict__ qh,
        const float* __restrict__ S, const float* __restrict__ colsum,
        float* __restrict__ attn_out)
{
    const int nblk = blockIdx.x;
    const int bh = blockIdx.y;
    const int b = bh >> 2, hg = bh & 3;
    const int tid = threadIdx.x;

    __shared__ float ctx[4096];
    for (int idx = tid; idx < 4096; idx += 256) {
        int dd = idx >> 6;
        ctx[idx] = S[(size_t)bh * 4096 + idx] / colsum[bh * 64 + dd];
    }
    __syncthreads();

    const int n = nblk * 256 + tid;
    const size_t rowidx = (((size_t)(b * NH + LH + hg)) * SEQ + n) * HD;
    const u16* qrow = qh + rowidx;

    float sumexp = 0.f;
    for (int c = 0; c < 8; c++) {
        uint4 v = *(const uint4*)(qrow + c * 8);
        const u16* u = (const u16*)&v;
        #pragma unroll
        for (int jj = 0; jj < 8; jj++) sumexp += __expf(b2f(u[jj]));
    }
    float inv = 0.125f / sumexp;

    f32x4 out4[16];
    #pragma unroll
    for (int t = 0; t < 16; t++)
        for (int i = 0; i < 4; i++) out4[t][i] = 0.f;

    for (int c = 0; c < 8; c++) {
        uint4 v = *(const uint4*)(qrow + c * 8);
        const u16* u = (const u16*)&v;
        #pragma unroll
        for (int jj = 0; jj < 8; jj++) {
            float pd = __expf(b2f(u[jj])) * inv;
            const f32x4* cr = (const f32x4*)&ctx[(c * 8 + jj) * 64];
            #pragma unroll
            for (int t = 0; t < 16; t++)
                out4[t] += pd * cr[t];
        }
    }

    float* ao = attn_out + rowidx;
    #pragma unroll
    for (int t = 0; t < 16; t++)
        *(f32x4*)(ao + t * 4) = out4[t];
}

// ---------------------------------------------------------------------------
// Kernel D: y = attn @ Wproj^T + bproj. attn read fp32, converted in-register.
// y written fp32 (overwrites xb/qb staging; both already consumed).
// ---------------------------------------------------------------------------
__global__ __launch_bounds__(256) void proj_gemm(const float* __restrict__ attn_out,
        const u16* __restrict__ Wproj, const float* __restrict__ bproj,
        float* __restrict__ y)
{
    const int wv = threadIdx.x >> 6, lane = threadIdx.x & 63;
    const int quad = lane >> 4, l16 = lane & 15;
    const int row0 = blockIdx.x * 64 + wv * 16;
    const int col0 = blockIdx.y * 128;

    const int m = row0 + l16;
    const int b = m >> 13, n = m & (SEQ - 1);

    f32x4 acc[8];
    #pragma unroll
    for (int t = 0; t < 8; t++)
        for (int i = 0; i < 4; i++) acc[t][i] = 0.f;

    for (int kk = 0; kk < DIM; kk += 32) {
        int h = kk >> 6;
        const float* arow = attn_out + (((size_t)(b * NH + h)) * SEQ + n) * HD + (kk & 63) + quad * 8;
        float4 f0 = *(const float4*)arow;
        float4 f1 = *(const float4*)(arow + 4);
        union { bf16x8 v; u16 u[8]; } A;
        A.u[0] = f2b(f0.x); A.u[1] = f2b(f0.y); A.u[2] = f2b(f0.z); A.u[3] = f2b(f0.w);
        A.u[4] = f2b(f1.x); A.u[5] = f2b(f1.y); A.u[6] = f2b(f1.z); A.u[7] = f2b(f1.w);
        #pragma unroll
        for (int t = 0; t < 8; t++) {
            bf16x8 bw = *(const bf16x8*)(Wproj + (size_t)(col0 + t * 16 + l16) * DIM + kk + quad * 8);
            acc[t] = __builtin_amdgcn_mfma_f32_16x16x32_bf16(A.v, bw, acc[t], 0, 0, 0);
        }
    }
    #pragma unroll
    for (int t = 0; t < 8; t++) {
        int col = col0 + t * 16 + l16;
        float bias = bproj[col];
        #pragma unroll
        for (int r = 0; r < 4; r++) {
            int row = row0 + quad * 4 + r;
            y[(size_t)row * DIM + col] = acc[t][r] + bias;
        }
    }
}

// ---------------------------------------------------------------------------
extern "C" void kernel_launch(void* const* d_in, const int* in_sizes, int n_in,
                              void* d_out, int out_size, void* d_ws, size_t ws_size,
                              hipStream_t stream)
{
    (void)in_sizes; (void)n_in; (void)out_size; (void)ws_size;
    const float* x     = (const float*)d_in[0];
    const float* Wq    = (const float*)d_in[1];
    const float* Wkv   = (const float*)d_in[2];
    const float* Wproj = (const float*)d_in[3];
    const float* bproj = (const float*)d_in[4];

    float* y        = (float*)d_out;                         // (B,N,C) fp32 = 67 MB
    float* attn_out = y + (size_t)BATCH * SEQ * DIM;         // (B,H,N,64) fp32 = 67 MB

    // stage bf16 x and q inside the y byte-region (both consumed before proj writes y)
    u16* xb = (u16*)y;                                       // 33.5 MB
    u16* qh = xb + (size_t)BATCH * SEQ * DIM;                // 33.5 MB

    char* ws = (char*)d_ws;
    float* S       = (float*)ws;                             // 262144 B
    float* colsum  = (float*)(ws + 262144);                  // 4096 B
    u16*   Wq_b    = (u16*)(ws + 266240);                    // 524288 B
    u16*   Wkv_b   = (u16*)(ws + 790528);                    // 524288 B
    u16*   Wproj_b = (u16*)(ws + 1314816);                   // 524288 B
    u16*   kh      = (u16*)(ws + 1839104);                   // 33,554,432 B
    // total ws usage: 35,393,536 B ≈ 35.4 MB

    const long NX = (long)BATCH * SEQ * DIM;   // 16,777,216
    const long NWT = (long)DIM * DIM;          // 262,144

    hipMemsetAsync(S, 0, 262144 + 4096, stream);
    convert_bf16<<<4096, 256, 0, stream>>>(x, xb, NX);
    convert_bf16<<<128, 256, 0, stream>>>(Wq, Wq_b, NWT);
    convert_bf16<<<128, 256, 0, stream>>>(Wkv, Wkv_b, NWT);
    convert_bf16<<<128, 256, 0, stream>>>(Wproj, Wproj_b, NWT);

    gemm_qk<<<dim3(512, 4), 256, 0, stream>>>(xb, Wq_b, Wkv_b, qh, kh);
    local_attn<<<dim3(NW, 16), 256, 0, stream>>>(qh, kh, attn_out);
    ctx_accum<<<dim3(16, 16), 256, 0, stream>>>(kh, S, colsum);
    global_out<<<dim3(32, 16), 256, 0, stream>>>(qh, S, colsum, attn_out);
    proj_gemm<<<dim3(512, 4), 256, 0, stream>>>(attn_out, Wproj_b, bproj, y);
}

// Round 5
// 477.932 us; speedup vs baseline: 1.7062x; 1.7062x over previous
//
#include <hip/hip_runtime.h>

#define DIM 512
#define NH 8
#define HD 64
#define LH 4
#define WIN 64
#define BATCH 4
#define SEQ 8192
#define NWIN (SEQ/WIN)   // 128

typedef unsigned short u16;
typedef __bf16 bf16x8 __attribute__((ext_vector_type(8)));
typedef float f32x4 __attribute__((ext_vector_type(4)));

__device__ __forceinline__ float b2f(u16 u) {
    return __uint_as_float(((unsigned int)u) << 16);
}
__device__ __forceinline__ u16 f2b(float f) {
    unsigned int x = __float_as_uint(f);
    return (u16)((x + 0x7FFFu + ((x >> 16) & 1u)) >> 16);
}

// async global->LDS, 16B per lane, lands at ldsbase + lane*16
__device__ __forceinline__ void gload16(const void* g, void* l) {
    __builtin_amdgcn_global_load_lds(
        (__attribute__((address_space(1))) void*)g,
        (__attribute__((address_space(3))) void*)l, 16, 0, 0);
}

// fp32 -> bf16 conversion
__global__ void convert_bf16(const float* __restrict__ src, u16* __restrict__ dst, long n)
{
    long i = ((long)blockIdx.x * 256 + threadIdx.x) * 8;
    const long stride = (long)gridDim.x * 256 * 8;
    for (; i < n; i += stride) {
        uint4 a = *(const uint4*)(src + i), b = *(const uint4*)(src + i + 4);
        const float* af = (const float*)&a;
        const float* bf_ = (const float*)&b;
        uint4 o; u16* ou = (u16*)&o;
        #pragma unroll
        for (int j = 0; j < 4; j++) { ou[j] = f2b(af[j]); ou[4 + j] = f2b(bf_[j]); }
        *(uint4*)(dst + i) = o;
    }
}

// ---------------------------------------------------------------------------
// Kernel A: [q|k] = x @ [Wq|Wkv]^T as one M=32768 x N=1024 x K=512 GEMM.
// m97 structure: 128x128 tile, BK=32, global_load_lds(16B), 4x4 MFMA acc/wave.
// Epilogue: per-wave LDS transpose -> coalesced 128B-row stores into the
// (B,NH,SEQ,HD) head-split bf16 layouts qh / kh.
// ---------------------------------------------------------------------------
__global__ __launch_bounds__(256) void gemm_qk_tiled(const u16* __restrict__ xb,
        const u16* __restrict__ Wqk, u16* __restrict__ qh, u16* __restrict__ kh)
{
    __shared__ __align__(16) u16 smem[16384];  // 32 KB: K-loop uses 16 KB, epilogue 32 KB
    u16* lA = smem;          // [128][32]
    u16* lB = smem + 4096;   // [128][32]

    const int tid = threadIdx.x;
    const int wv = tid >> 6, lane = tid & 63;
    const int quad = lane >> 4, l16 = lane & 15;
    const int wr = wv >> 1, wc = wv & 1;
    const int row0 = blockIdx.y * 128;
    const int col0 = blockIdx.x * 128;
    const int lrow = lane >> 2, lkc = (lane & 3) * 8;

    f32x4 acc[4][4];
    #pragma unroll
    for (int t = 0; t < 4; t++)
        for (int u = 0; u < 4; u++)
            for (int i = 0; i < 4; i++) acc[t][u][i] = 0.f;

    const u16* gA = xb  + (size_t)(row0 + lrow) * DIM + lkc;
    const u16* gB = Wqk + (size_t)(col0 + lrow) * DIM + lkc;

    for (int kt = 0; kt < DIM; kt += 32) {
        __syncthreads();
        #pragma unroll
        for (int i = 0; i < 2; i++) {
            int rb = wv * 32 + i * 16;
            gload16(gA + (size_t)rb * DIM + kt, &lA[rb * 32]);
            gload16(gB + (size_t)rb * DIM + kt, &lB[rb * 32]);
        }
        __syncthreads();
        bf16x8 af[4], bfr[4];
        #pragma unroll
        for (int t = 0; t < 4; t++)
            af[t] = *(const bf16x8*)&lA[(wr * 64 + t * 16 + l16) * 32 + quad * 8];
        #pragma unroll
        for (int u = 0; u < 4; u++)
            bfr[u] = *(const bf16x8*)&lB[(wc * 64 + u * 16 + l16) * 32 + quad * 8];
        #pragma unroll
        for (int t = 0; t < 4; t++)
            #pragma unroll
            for (int u = 0; u < 4; u++)
                acc[t][u] = __builtin_amdgcn_mfma_f32_16x16x32_bf16(af[t], bfr[u], acc[t][u], 0, 0, 0);
    }

    // epilogue: wave-local 64x64 bf16 C-tile in LDS, then coalesced stores
    __syncthreads();
    u16* cw = smem + wv * 4096;
    #pragma unroll
    for (int t = 0; t < 4; t++)
        #pragma unroll
        for (int u = 0; u < 4; u++)
            #pragma unroll
            for (int r = 0; r < 4; r++)
                cw[(t * 16 + quad * 4 + r) * 64 + u * 16 + l16] = f2b(acc[t][u][r]);

    const int colg0 = col0 + wc * 64;            // wave's 64 cols = one full head
    const int seg = lane & 7;
    u16* dstbase;
    {
        int h = (colg0 & 511) >> 6;
        u16* base = (colg0 < 512) ? qh : kh;
        dstbase = base + (size_t)h * SEQ * HD;   // + b*NH*SEQ*HD later
    }
    #pragma unroll
    for (int i = 0; i < 8; i++) {
        int mm = i * 8 + (lane >> 3);
        uint4 v = *(const uint4*)&cw[mm * 64 + seg * 8];
        int m = row0 + wr * 64 + mm;
        int bb = m >> 13, nn = m & (SEQ - 1);
        *(uint4*)(dstbase + ((size_t)bb * NH * SEQ + nn) * HD + seg * 8) = v;
    }
}

// ---------------------------------------------------------------------------
// Kernel B: local attention (unchanged from R4; next optimization target).
// ---------------------------------------------------------------------------
#define KJ_STRIDE 72
#define KT_STRIDE 200

__global__ __launch_bounds__(256) void local_attn(const u16* __restrict__ qh,
        const u16* __restrict__ kh, float* __restrict__ attn_out)
{
    __shared__ __align__(16) u16 kjP[192 * KJ_STRIDE];
    __shared__ __align__(16) u16 kT[64 * KT_STRIDE];

    const int w = blockIdx.x;
    const int bh = blockIdx.y;
    const int b = bh >> 2, h = bh & 3;
    const int tid = threadIdx.x;
    const int wv = tid >> 6, lane = tid & 63;
    const int quad = lane >> 4, l16 = lane & 15;

    for (int idx = tid; idx < 192 * 8; idx += 256) {
        int j = idx >> 3, dc = (idx & 7) << 3;
        int n = w * WIN - WIN + j;
        uint4 val = make_uint4(0, 0, 0, 0);
        if (n >= 0 && n < SEQ)
            val = *(const uint4*)(kh + (((size_t)(b * NH + h)) * SEQ + n) * HD + dc);
        *(uint4*)(&kjP[j * KJ_STRIDE + dc]) = val;
    }
    __syncthreads();
    for (int idx = tid; idx < 64 * 192; idx += 256) {
        int e = idx & 63, j = idx >> 6;
        kT[e * KT_STRIDE + j] = kjP[j * KJ_STRIDE + e];
    }
    __syncthreads();

    f32x4 s[12];
    #pragma unroll
    for (int t = 0; t < 12; t++)
        for (int i = 0; i < 4; i++) s[t][i] = 0.f;

    const u16* qrow = qh + (((size_t)(b * NH + h)) * SEQ + w * WIN + wv * 16 + l16) * HD + quad * 8;
    #pragma unroll
    for (int kk = 0; kk < 64; kk += 32) {
        bf16x8 a = *(const bf16x8*)(qrow + kk);
        #pragma unroll
        for (int t = 0; t < 12; t++) {
            bf16x8 bf = *(const bf16x8*)(&kjP[(t * 16 + l16) * KJ_STRIDE + kk + quad * 8]);
            s[t] = __builtin_amdgcn_mfma_f32_16x16x32_bf16(a, bf, s[t], 0, 0, 0);
        }
    }
    __syncthreads();

    const float scale = 0.125f;
    #pragma unroll
    for (int r = 0; r < 4; r++) {
        float vals[12];
        float mx = -3.0e38f;
        #pragma unroll
        for (int t = 0; t < 12; t++) {
            int j = t * 16 + l16;
            float v = s[t][r] * scale;
            bool valid = !((w == 0 && j < 64) || (w == NWIN - 1 && j >= 128));
            v = valid ? v : -30000.0f;
            vals[t] = v;
            mx = fmaxf(mx, v);
        }
        for (int m = 1; m <= 8; m <<= 1) mx = fmaxf(mx, __shfl_xor(mx, m));
        float sum = 0.f;
        #pragma unroll
        for (int t = 0; t < 12; t++) { vals[t] = __expf(vals[t] - mx); sum += vals[t]; }
        for (int m = 1; m <= 8; m <<= 1) sum += __shfl_xor(sum, m);
        float inv = 1.0f / sum;
        int prow = wv * 16 + quad * 4 + r;
        #pragma unroll
        for (int t = 0; t < 12; t++)
            kjP[prow * KT_STRIDE + t * 16 + l16] = f2b(vals[t] * inv);
    }
    __syncthreads();

    f32x4 o[4];
    #pragma unroll
    for (int t = 0; t < 4; t++)
        for (int i = 0; i < 4; i++) o[t][i] = 0.f;
    #pragma unroll
    for (int kc = 0; kc < 6; kc++) {
        bf16x8 a = *(const bf16x8*)(&kjP[(wv * 16 + l16) * KT_STRIDE + kc * 32 + quad * 8]);
        #pragma unroll
        for (int t = 0; t < 4; t++) {
            bf16x8 bf = *(const bf16x8*)(&kT[(t * 16 + l16) * KT_STRIDE + kc * 32 + quad * 8]);
            o[t] = __builtin_amdgcn_mfma_f32_16x16x32_bf16(a, bf, o[t], 0, 0, 0);
        }
    }
    #pragma unroll
    for (int t = 0; t < 4; t++) {
        int e = t * 16 + l16;
        #pragma unroll
        for (int r = 0; r < 4; r++) {
            int n = w * WIN + wv * 16 + quad * 4 + r;
            attn_out[(((size_t)(b * NH + h)) * SEQ + n) * HD + e] = o[t][r];
        }
    }
}

// ---------------------------------------------------------------------------
// Kernel C1: linear attention context accumulate (unchanged).
// ---------------------------------------------------------------------------
__global__ __launch_bounds__(256) void ctx_accum(const u16* __restrict__ kh,
        float* __restrict__ S, float* __restrict__ colsum)
{
    const int chunk = blockIdx.x;
    const int bh = blockIdx.y;
    const int b = bh >> 2, hg = bh & 3;
    const int tid = threadIdx.x;
    const int d = tid >> 2, esub = tid & 3;
    const int r0 = tid >> 6, d2 = tid & 63;

    __shared__ float kraw[4][64];
    __shared__ float kexp[4][64];

    float acc[16];
    #pragma unroll
    for (int i = 0; i < 16; i++) acc[i] = 0.f;
    float csum = 0.f;

    const u16* kbase = kh + ((size_t)(b * NH + LH + hg)) * SEQ * HD;
    for (int n0 = chunk * 512; n0 < chunk * 512 + 512; n0 += 4) {
        __syncthreads();
        float v = b2f(kbase[(size_t)(n0 + r0) * HD + d2]);
        kraw[r0][d2] = v;
        kexp[r0][d2] = __expf(v);
        __syncthreads();
        #pragma unroll
        for (int r = 0; r < 4; r++) {
            float pd = kexp[r][d];
            if (esub == 0) csum += pd;
            #pragma unroll
            for (int j = 0; j < 4; j++) {
                f32x4 kv = *(const f32x4*)(&kraw[r][esub * 16 + j * 4]);
                acc[j * 4 + 0] += pd * kv[0];
                acc[j * 4 + 1] += pd * kv[1];
                acc[j * 4 + 2] += pd * kv[2];
                acc[j * 4 + 3] += pd * kv[3];
            }
        }
    }
    float* Sp = S + (size_t)bh * 4096 + d * 64 + esub * 16;
    #pragma unroll
    for (int i = 0; i < 16; i++) atomicAdd(Sp + i, acc[i]);
    if (esub == 0) atomicAdd(colsum + bh * 64 + d, csum);
}

// ---------------------------------------------------------------------------
// Kernel C2: linear attention output (unchanged).
// ---------------------------------------------------------------------------
__global__ __launch_bounds__(256) void global_out(const u16* __restrict__ qh,
        const float* __restrict__ S, const float* __restrict__ colsum,
        float* __restrict__ attn_out)
{
    const int nblk = blockIdx.x;
    const int bh = blockIdx.y;
    const int b = bh >> 2, hg = bh & 3;
    const int tid = threadIdx.x;

    __shared__ float ctx[4096];
    for (int idx = tid; idx < 4096; idx += 256) {
        int dd = idx >> 6;
        ctx[idx] = S[(size_t)bh * 4096 + idx] / colsum[bh * 64 + dd];
    }
    __syncthreads();

    const int n = nblk * 256 + tid;
    const size_t rowidx = (((size_t)(b * NH + LH + hg)) * SEQ + n) * HD;
    const u16* qrow = qh + rowidx;

    float sumexp = 0.f;
    for (int c = 0; c < 8; c++) {
        uint4 v = *(const uint4*)(qrow + c * 8);
        const u16* u = (const u16*)&v;
        #pragma unroll
        for (int jj = 0; jj < 8; jj++) sumexp += __expf(b2f(u[jj]));
    }
    float inv = 0.125f / sumexp;

    f32x4 out4[16];
    #pragma unroll
    for (int t = 0; t < 16; t++)
        for (int i = 0; i < 4; i++) out4[t][i] = 0.f;

    for (int c = 0; c < 8; c++) {
        uint4 v = *(const uint4*)(qrow + c * 8);
        const u16* u = (const u16*)&v;
        #pragma unroll
        for (int jj = 0; jj < 8; jj++) {
            float pd = __expf(b2f(u[jj])) * inv;
            const f32x4* cr = (const f32x4*)&ctx[(c * 8 + jj) * 64];
            #pragma unroll
            for (int t = 0; t < 16; t++)
                out4[t] += pd * cr[t];
        }
    }

    float* ao = attn_out + rowidx;
    #pragma unroll
    for (int t = 0; t < 16; t++)
        *(f32x4*)(ao + t * 4) = out4[t];
}

// ---------------------------------------------------------------------------
// Kernel D: y = attn @ Wproj^T + bproj, LDS-tiled. A (fp32 attn, head-split)
// staged via reg-convert->ds_write; B (bf16 Wproj) via global_load_lds.
// ---------------------------------------------------------------------------
__global__ __launch_bounds__(256) void proj_gemm_tiled(const float* __restrict__ attn_out,
        const u16* __restrict__ Wproj, const float* __restrict__ bproj,
        float* __restrict__ y)
{
    __shared__ __align__(16) u16 smem[8192];   // 16 KB: lA 8 KB + lB 8 KB
    u16* lA = smem;          // [128][32]
    u16* lB = smem + 4096;   // [128][32]

    const int tid = threadIdx.x;
    const int wv = tid >> 6, lane = tid & 63;
    const int quad = lane >> 4, l16 = lane & 15;
    const int wr = wv >> 1, wc = wv & 1;
    const int row0 = blockIdx.y * 128;
    const int col0 = blockIdx.x * 128;
    const int lrow = lane >> 2, lkc = (lane & 3) * 8;

    f32x4 acc[4][4];
    #pragma unroll
    for (int t = 0; t < 4; t++)
        for (int u = 0; u < 4; u++)
            for (int i = 0; i < 4; i++) acc[t][u][i] = 0.f;

    const u16* gB = Wproj + (size_t)(col0 + lrow) * DIM + lkc;

    for (int kt = 0; kt < DIM; kt += 32) {
        const int h = kt >> 6;               // k-chunk stays within one head
        const int e0 = (kt & 63) + lkc;
        __syncthreads();
        #pragma unroll
        for (int i = 0; i < 2; i++) {
            int rb = wv * 32 + i * 16;
            // B via async direct-to-LDS
            gload16(gB + (size_t)rb * DIM + kt, &lB[rb * 32]);
            // A: fp32 -> bf16 through registers
            int m = row0 + rb + lrow;
            int bb = m >> 13, nn = m & (SEQ - 1);
            const float* ga = attn_out + (((size_t)(bb * NH + h)) * SEQ + nn) * HD + e0;
            uint4 f0 = *(const uint4*)ga;
            uint4 f1 = *(const uint4*)(ga + 4);
            const float* a0 = (const float*)&f0;
            const float* a1 = (const float*)&f1;
            uint4 o; u16* ou = (u16*)&o;
            #pragma unroll
            for (int j = 0; j < 4; j++) { ou[j] = f2b(a0[j]); ou[4 + j] = f2b(a1[j]); }
            *(uint4*)&lA[(rb + lrow) * 32 + lkc] = o;
        }
        __syncthreads();
        bf16x8 af[4], bfr[4];
        #pragma unroll
        for (int t = 0; t < 4; t++)
            af[t] = *(const bf16x8*)&lA[(wr * 64 + t * 16 + l16) * 32 + quad * 8];
        #pragma unroll
        for (int u = 0; u < 4; u++)
            bfr[u] = *(const bf16x8*)&lB[(wc * 64 + u * 16 + l16) * 32 + quad * 8];
        #pragma unroll
        for (int t = 0; t < 4; t++)
            #pragma unroll
            for (int u = 0; u < 4; u++)
                acc[t][u] = __builtin_amdgcn_mfma_f32_16x16x32_bf16(af[t], bfr[u], acc[t][u], 0, 0, 0);
    }

    #pragma unroll
    for (int u = 0; u < 4; u++) {
        int col = col0 + wc * 64 + u * 16 + l16;
        float bias = bproj[col];
        #pragma unroll
        for (int t = 0; t < 4; t++)
            #pragma unroll
            for (int r = 0; r < 4; r++) {
                int m = row0 + wr * 64 + t * 16 + quad * 4 + r;
                y[(size_t)m * DIM + col] = acc[t][u][r] + bias;
            }
    }
}

// ---------------------------------------------------------------------------
extern "C" void kernel_launch(void* const* d_in, const int* in_sizes, int n_in,
                              void* d_out, int out_size, void* d_ws, size_t ws_size,
                              hipStream_t stream)
{
    (void)in_sizes; (void)n_in; (void)out_size; (void)ws_size;
    const float* x     = (const float*)d_in[0];
    const float* Wq    = (const float*)d_in[1];
    const float* Wkv   = (const float*)d_in[2];
    const float* Wproj = (const float*)d_in[3];
    const float* bproj = (const float*)d_in[4];

    float* y        = (float*)d_out;                         // (B,N,C) fp32
    float* attn_out = y + (size_t)BATCH * SEQ * DIM;         // (B,H,N,64) fp32

    // bf16 x and q staged in the y byte-region (consumed before proj writes y)
    u16* xb = (u16*)y;                                       // 33.5 MB
    u16* qh = xb + (size_t)BATCH * SEQ * DIM;                // 33.5 MB

    char* ws = (char*)d_ws;
    float* S       = (float*)ws;                             // 262144 B
    float* colsum  = (float*)(ws + 262144);                  // 4096 B
    u16*   Wqk     = (u16*)(ws + 266240);                    // 1024x512 bf16 = 1 MB
    u16*   Wproj_b = (u16*)(ws + 266240 + 1048576);          // 512 KB
    u16*   kh      = (u16*)(ws + 266240 + 1048576 + 524288); // 33.5 MB
    // total ws usage ≈ 35.4 MB

    const long NX = (long)BATCH * SEQ * DIM;   // 16,777,216
    const long NWT = (long)DIM * DIM;          // 262,144

    hipMemsetAsync(S, 0, 262144 + 4096, stream);
    convert_bf16<<<4096, 256, 0, stream>>>(x, xb, NX);
    convert_bf16<<<128, 256, 0, stream>>>(Wq, Wqk, NWT);          // cols 0..511   -> q
    convert_bf16<<<128, 256, 0, stream>>>(Wkv, Wqk + NWT, NWT);   // cols 512..1023-> k
    convert_bf16<<<128, 256, 0, stream>>>(Wproj, Wproj_b, NWT);

    gemm_qk_tiled<<<dim3(8, 256), 256, 0, stream>>>(xb, Wqk, qh, kh);
    local_attn<<<dim3(NWIN, 16), 256, 0, stream>>>(qh, kh, attn_out);
    ctx_accum<<<dim3(16, 16), 256, 0, stream>>>(kh, S, colsum);
    global_out<<<dim3(32, 16), 256, 0, stream>>>(qh, S, colsum, attn_out);
    proj_gemm_tiled<<<dim3(4, 256), 256, 0, stream>>>(attn_out, Wproj_b, bproj, y);
}